// Round 1
// baseline (188.160 us; speedup 1.0000x reference)
//
#include <hip/hip_runtime.h>
#include <hip/hip_bf16.h>

#define N_ROWS 8192
#define DIM 256
#define NUM_CLASSES 64

typedef __bf16 bf16x8 __attribute__((ext_vector_type(8)));
typedef float f32x4 __attribute__((ext_vector_type(4)));

__device__ __forceinline__ unsigned short f2bf(float f) {
  unsigned int u = __float_as_uint(f);
  u += 0x7fffu + ((u >> 16) & 1u);   // round-to-nearest-even
  return (unsigned short)(u >> 16);
}
__device__ __forceinline__ float bf2f(unsigned short h) {
  return __uint_as_float(((unsigned int)h) << 16);
}

__device__ __forceinline__ void gload_lds16(const unsigned short* g, unsigned short* l) {
  __builtin_amdgcn_global_load_lds(
      (const __attribute__((address_space(1))) unsigned int*)g,
      (__attribute__((address_space(3))) unsigned int*)l, 16, 0, 0);
}

// Kernel 1: per-row sum-of-squares of the *quantized* values (keeps diagonal
// cos exactly 1), scale s_i = sqrt((log2e/t) / ss_i), bf16 cast, label histogram.
__global__ void __launch_bounds__(256) prep_kernel(
    const float* __restrict__ x, const int* __restrict__ lab,
    const float* __restrict__ tptr,
    unsigned short* __restrict__ xb, float* __restrict__ sv,
    int* __restrict__ counts) {
  const int row = blockIdx.x * 4 + (threadIdx.x >> 6);
  const int lane = threadIdx.x & 63;
  const float4 v = *reinterpret_cast<const float4*>(x + (size_t)row * DIM + lane * 4);
  const unsigned short q0 = f2bf(v.x), q1 = f2bf(v.y), q2 = f2bf(v.z), q3 = f2bf(v.w);
  const float f0 = bf2f(q0), f1 = bf2f(q1), f2 = bf2f(q2), f3 = bf2f(q3);
  float ss = f0 * f0 + f1 * f1 + f2 * f2 + f3 * f3;
  ushort4 u4; u4.x = q0; u4.y = q1; u4.z = q2; u4.w = q3;
  *reinterpret_cast<ushort4*>(xb + (size_t)row * DIM + lane * 4) = u4;
  for (int m = 32; m; m >>= 1) ss += __shfl_xor(ss, m, 64);
  if (lane == 0) {
    const float C = 1.4426950408889634f / tptr[0];  // log2(e)/t
    sv[row] = sqrtf(C / ss);
    atomicAdd(&counts[lab[row]], 1);
  }
}

// Kernel 2: 128x128-tile Gram GEMM (bf16 MFMA 16x16x32), fused epilogue:
// e = exp2(dot * s_i * s_j); per-row masked sums -> per-(col-block,row) partials.
__global__ void __launch_bounds__(256) main_kernel(
    const unsigned short* __restrict__ xb, const float* __restrict__ sv,
    const int* __restrict__ lab, float* __restrict__ part) {
  __shared__ alignas(16) unsigned short Alds[128 * 32];
  __shared__ alignas(16) unsigned short Blds[128 * 32];
  __shared__ float red[256];  // [0:128)=S_tot, [128:256)=S_same per local row

  const int tid = threadIdx.x;
  const int wave = tid >> 6;
  const int lane = tid & 63;
  const int quad = lane >> 4;   // 0..3
  const int lc = lane & 15;     // 0..15
  const int wrow = (wave >> 1) * 64;
  const int wcol = (wave & 1) * 64;
  const int rowBase = blockIdx.y * 128;
  const int colBase = blockIdx.x * 128;

  f32x4 acc[4][4];
  const f32x4 zero4 = {0.f, 0.f, 0.f, 0.f};
  for (int mi = 0; mi < 4; ++mi)
    for (int ni = 0; ni < 4; ++ni) acc[mi][ni] = zero4;

  const int srow = lane >> 2;       // staging: 16 rows per instruction
  const int sseg = (lane & 3) * 8;  // 4 x 16B segments per 32-elem row

  for (int kb = 0; kb < 8; ++kb) {
    const int k0 = kb * 32;
    {
      const unsigned short* gA =
          xb + (size_t)(rowBase + wave * 32 + srow) * DIM + k0 + sseg;
      gload_lds16(gA, &Alds[(wave * 32) * 32]);
      gload_lds16(gA + 16 * DIM, &Alds[(wave * 32 + 16) * 32]);
      const unsigned short* gB =
          xb + (size_t)(colBase + wave * 32 + srow) * DIM + k0 + sseg;
      gload_lds16(gB, &Blds[(wave * 32) * 32]);
      gload_lds16(gB + 16 * DIM, &Blds[(wave * 32 + 16) * 32]);
    }
    __syncthreads();
    bf16x8 afr[4], bfr[4];
    for (int mi = 0; mi < 4; ++mi)
      afr[mi] = *reinterpret_cast<const bf16x8*>(
          &Alds[(wrow + mi * 16 + lc) * 32 + quad * 8]);
    for (int ni = 0; ni < 4; ++ni)
      bfr[ni] = *reinterpret_cast<const bf16x8*>(
          &Blds[(wcol + ni * 16 + lc) * 32 + quad * 8]);
    for (int mi = 0; mi < 4; ++mi)
      for (int ni = 0; ni < 4; ++ni)
        acc[mi][ni] = __builtin_amdgcn_mfma_f32_16x16x32_bf16(
            afr[mi], bfr[ni], acc[mi][ni], 0, 0, 0);
    __syncthreads();
  }

  red[tid] = 0.f;
  __syncthreads();

  float scol[4];
  int labc[4];
  for (int ni = 0; ni < 4; ++ni) {
    const int c = colBase + wcol + ni * 16 + lc;
    scol[ni] = sv[c];
    labc[ni] = lab[c];
  }

  for (int mi = 0; mi < 4; ++mi) {
    for (int r = 0; r < 4; ++r) {
      const int lr = wrow + mi * 16 + quad * 4 + r;  // C/D: row=(lane>>4)*4+reg
      const int grow = rowBase + lr;
      const float si = sv[grow];
      const int li = lab[grow];
      float st = 0.f, sm = 0.f;
      for (int ni = 0; ni < 4; ++ni) {
        const float e = exp2f(acc[mi][ni][r] * si * scol[ni]);
        st += e;
        sm += (li == labc[ni]) ? e : 0.f;
      }
      // reduce over the 16 lanes (lc bits 0..3) holding this row's columns
      for (int m = 8; m; m >>= 1) {
        st += __shfl_xor(st, m, 64);
        sm += __shfl_xor(sm, m, 64);
      }
      if (lc == 0) {
        atomicAdd(&red[lr], st);
        atomicAdd(&red[128 + lr], sm);
      }
    }
  }
  __syncthreads();
  if (tid < 128) {
    part[(size_t)blockIdx.x * N_ROWS + rowBase + tid] = red[tid];
    part[(size_t)(64 + blockIdx.x) * N_ROWS + rowBase + tid] = red[128 + tid];
  }
}

// Kernel 3: per-row loss terms, reduced to one partial per block.
__global__ void __launch_bounds__(256) row_loss_kernel(
    const float* __restrict__ part, const int* __restrict__ lab,
    const int* __restrict__ counts, float* __restrict__ bsum) {
  const int row = blockIdx.x * 256 + threadIdx.x;
  float st = 0.f, sm = 0.f;
  for (int b = 0; b < 64; ++b) {
    st += part[(size_t)b * N_ROWS + row];
    sm += part[(size_t)(64 + b) * N_ROWS + row];
  }
  const int c = counts[lab[row]];
  const float pos = sm + (float)(N_ROWS - c);
  const float neg = (st - sm) + (float)c;
  float term = logf(neg) - logf(pos);
  for (int m = 32; m; m >>= 1) term += __shfl_xor(term, m, 64);
  __shared__ float wsum[4];
  const int lane = threadIdx.x & 63;
  const int wave = threadIdx.x >> 6;
  if (lane == 0) wsum[wave] = term;
  __syncthreads();
  if (threadIdx.x == 0) bsum[blockIdx.x] = wsum[0] + wsum[1] + wsum[2] + wsum[3];
}

// Kernel 4: final 32-value reduction -> scalar loss.
__global__ void final_kernel(const float* __restrict__ bsum, float* __restrict__ out) {
  float v = (threadIdx.x < 32) ? bsum[threadIdx.x] : 0.f;
  for (int m = 32; m; m >>= 1) v += __shfl_xor(v, m, 64);
  if (threadIdx.x == 0) out[0] = v * (1.0f / (float)N_ROWS);
}

extern "C" void kernel_launch(void* const* d_in, const int* in_sizes, int n_in,
                              void* d_out, int out_size, void* d_ws, size_t ws_size,
                              hipStream_t stream) {
  const float* x = (const float*)d_in[0];
  const int* lab = (const int*)d_in[1];
  const float* t = (const float*)d_in[2];
  float* out = (float*)d_out;

  char* ws = (char*)d_ws;
  unsigned short* xb = (unsigned short*)ws;                      // 4 MiB bf16 X
  float* sv = (float*)(ws + (4u << 20));                         // 32 KiB scales
  float* part = (float*)(ws + (4u << 20) + (32u << 10));         // 4 MiB partials
  int* counts = (int*)(ws + (8u << 20) + (32u << 10));           // 256 B
  float* bsum = (float*)(ws + (8u << 20) + (33u << 10));         // 128 B

  hipMemsetAsync(counts, 0, NUM_CLASSES * sizeof(int), stream);
  prep_kernel<<<N_ROWS / 4, 256, 0, stream>>>(x, lab, t, xb, sv, counts);
  dim3 grid(64, 64);
  main_kernel<<<grid, 256, 0, stream>>>(xb, sv, lab, part);
  row_loss_kernel<<<N_ROWS / 256, 256, 0, stream>>>(part, lab, counts, bsum);
  final_kernel<<<1, 64, 0, stream>>>(bsum, out);
}

// Round 2
// 145.400 us; speedup vs baseline: 1.2941x; 1.2941x over previous
//
#include <hip/hip_runtime.h>
#include <hip/hip_bf16.h>

#define N_ROWS 8192
#define DIM 256
#define NUM_CLASSES 64

typedef __bf16 bf16x8 __attribute__((ext_vector_type(8)));
typedef float f32x4 __attribute__((ext_vector_type(4)));

__device__ __forceinline__ unsigned short f2bf(float f) {
  unsigned int u = __float_as_uint(f);
  u += 0x7fffu + ((u >> 16) & 1u);   // round-to-nearest-even
  return (unsigned short)(u >> 16);
}
__device__ __forceinline__ float bf2f(unsigned short h) {
  return __uint_as_float(((unsigned int)h) << 16);
}

__device__ __forceinline__ void gload_lds16(const unsigned short* g, unsigned short* l) {
  __builtin_amdgcn_global_load_lds(
      (const __attribute__((address_space(1))) unsigned int*)g,
      (__attribute__((address_space(3))) unsigned int*)l, 16, 0, 0);
}

// Kernel 1: per-row sum-of-squares of the *quantized* values (keeps diagonal
// cos exact), scale s_i = sqrt((log2e/t) / ss_i), bf16 cast.
__global__ void __launch_bounds__(256) prep_kernel(
    const float* __restrict__ x, const float* __restrict__ tptr,
    unsigned short* __restrict__ xb, float* __restrict__ sv) {
  const int row = blockIdx.x * 4 + (threadIdx.x >> 6);
  const int lane = threadIdx.x & 63;
  const float4 v = *reinterpret_cast<const float4*>(x + (size_t)row * DIM + lane * 4);
  const unsigned short q0 = f2bf(v.x), q1 = f2bf(v.y), q2 = f2bf(v.z), q3 = f2bf(v.w);
  const float f0 = bf2f(q0), f1 = bf2f(q1), f2 = bf2f(q2), f3 = bf2f(q3);
  float ss = f0 * f0 + f1 * f1 + f2 * f2 + f3 * f3;
  ushort4 u4; u4.x = q0; u4.y = q1; u4.z = q2; u4.w = q3;
  *reinterpret_cast<ushort4*>(xb + (size_t)row * DIM + lane * 4) = u4;
  for (int m = 32; m; m >>= 1) ss += __shfl_xor(ss, m, 64);
  if (lane == 0) {
    const float C = 1.4426950408889634f / tptr[0];  // log2(e)/t
    sv[row] = sqrtf(C / ss);
  }
}

// Kernel 2: upper-triangle 128x128 Gram tiles (bf16 MFMA 16x16x32), pipelined
// double-buffered staging, fused exp epilogue producing BOTH row partials
// (for rowblock I over cols J) and col partials (for rowblock J over cols I).
__global__ void __launch_bounds__(256) main_kernel(
    const unsigned short* __restrict__ xb, const float* __restrict__ sv,
    const int* __restrict__ lab, float* __restrict__ part) {
  const int I = blockIdx.y, J = blockIdx.x;
  if (J < I) return;

  __shared__ alignas(16) unsigned short Alds[2][128 * 32];
  __shared__ alignas(16) unsigned short Blds[2][128 * 32];
  __shared__ float red[256];            // [0:128)=S_tot, [128:256)=S_same per row
  __shared__ float colred[2][128][2];   // [tot/same][col][rowhalf]

  const int tid = threadIdx.x;
  const int wave = tid >> 6;
  const int lane = tid & 63;
  const int quad = lane >> 4;
  const int lc = lane & 15;
  const int wrow = (wave >> 1) * 64;
  const int wcol = (wave & 1) * 64;
  const int rowBase = I * 128;
  const int colBase = J * 128;

  red[tid] = 0.f;

  f32x4 acc[4][4];
  const f32x4 zero4 = {0.f, 0.f, 0.f, 0.f};
  for (int mi = 0; mi < 4; ++mi)
    for (int ni = 0; ni < 4; ++ni) acc[mi][ni] = zero4;

  const int srow = lane >> 2;       // 16 rows per staging instruction
  const int sseg = (lane & 3) * 8;  // 4 x 16B segments per 32-elem row

#define STAGE(kb, b)                                                          \
  {                                                                           \
    const int k0 = (kb) * 32;                                                 \
    const unsigned short* gA =                                                \
        xb + (size_t)(rowBase + wave * 32 + srow) * DIM + k0 + sseg;          \
    gload_lds16(gA, &Alds[b][(wave * 32) * 32]);                              \
    gload_lds16(gA + 16 * DIM, &Alds[b][(wave * 32 + 16) * 32]);              \
    const unsigned short* gB =                                                \
        xb + (size_t)(colBase + wave * 32 + srow) * DIM + k0 + sseg;          \
    gload_lds16(gB, &Blds[b][(wave * 32) * 32]);                              \
    gload_lds16(gB + 16 * DIM, &Blds[b][(wave * 32 + 16) * 32]);              \
  }

  STAGE(0, 0)
  for (int kb = 0; kb < 8; ++kb) {
    __syncthreads();  // staging(kb) complete; prior buffer's readers done
    if (kb < 7) STAGE(kb + 1, (kb + 1) & 1)
    const unsigned short* Ab = &Alds[kb & 1][0];
    const unsigned short* Bb = &Blds[kb & 1][0];
    bf16x8 afr[4], bfr[4];
    for (int mi = 0; mi < 4; ++mi)
      afr[mi] = *reinterpret_cast<const bf16x8*>(
          &Ab[(wrow + mi * 16 + lc) * 32 + quad * 8]);
    for (int ni = 0; ni < 4; ++ni)
      bfr[ni] = *reinterpret_cast<const bf16x8*>(
          &Bb[(wcol + ni * 16 + lc) * 32 + quad * 8]);
    for (int mi = 0; mi < 4; ++mi)
      for (int ni = 0; ni < 4; ++ni)
        acc[mi][ni] = __builtin_amdgcn_mfma_f32_16x16x32_bf16(
            afr[mi], bfr[ni], acc[mi][ni], 0, 0, 0);
  }
#undef STAGE

  float scol[4];
  int labc[4];
  for (int ni = 0; ni < 4; ++ni) {
    const int c = colBase + wcol + ni * 16 + lc;
    scol[ni] = sv[c];
    labc[ni] = lab[c];
  }
  float ctot[4] = {0.f, 0.f, 0.f, 0.f};
  float csame[4] = {0.f, 0.f, 0.f, 0.f};

  for (int mi = 0; mi < 4; ++mi) {
    for (int r = 0; r < 4; ++r) {
      const int lr = wrow + mi * 16 + quad * 4 + r;  // C/D: row=(lane>>4)*4+reg
      const int grow = rowBase + lr;
      const float si = sv[grow];
      const int li = lab[grow];
      float st = 0.f, sm = 0.f;
      for (int ni = 0; ni < 4; ++ni) {
        const float e = exp2f(acc[mi][ni][r] * si * scol[ni]);
        const float em = (li == labc[ni]) ? e : 0.f;
        st += e;
        sm += em;
        ctot[ni] += e;
        csame[ni] += em;
      }
      for (int m = 8; m; m >>= 1) {
        st += __shfl_xor(st, m, 64);
        sm += __shfl_xor(sm, m, 64);
      }
      if (lc == 0) {
        atomicAdd(&red[lr], st);
        atomicAdd(&red[128 + lr], sm);
      }
    }
  }

  if (J > I) {
    for (int ni = 0; ni < 4; ++ni) {
      float t2 = ctot[ni] + __shfl_xor(ctot[ni], 16, 64);
      t2 += __shfl_xor(t2, 32, 64);
      float s2 = csame[ni] + __shfl_xor(csame[ni], 16, 64);
      s2 += __shfl_xor(s2, 32, 64);
      if (quad == 0) {
        colred[0][wcol + ni * 16 + lc][wave >> 1] = t2;
        colred[1][wcol + ni * 16 + lc][wave >> 1] = s2;
      }
    }
  }
  __syncthreads();
  if (tid < 128) {
    part[(size_t)J * N_ROWS + rowBase + tid] = red[tid];
    part[(size_t)(64 + J) * N_ROWS + rowBase + tid] = red[128 + tid];
    if (J > I) {
      part[(size_t)I * N_ROWS + colBase + tid] =
          colred[0][tid][0] + colred[0][tid][1];
      part[(size_t)(64 + I) * N_ROWS + colBase + tid] =
          colred[1][tid][0] + colred[1][tid][1];
    }
  }
}

// Kernel 3: per-row loss terms (label histogram built in LDS), one partial/block.
__global__ void __launch_bounds__(256) row_loss_kernel(
    const float* __restrict__ part, const int* __restrict__ lab,
    float* __restrict__ bsum) {
  __shared__ int h[NUM_CLASSES];
  if (threadIdx.x < NUM_CLASSES) h[threadIdx.x] = 0;
  __syncthreads();
  for (int i = threadIdx.x; i < N_ROWS; i += 256) atomicAdd(&h[lab[i]], 1);
  __syncthreads();

  const int row = blockIdx.x * 256 + threadIdx.x;
  float st = 0.f, sm = 0.f;
  for (int b = 0; b < 64; ++b) {
    st += part[(size_t)b * N_ROWS + row];
    sm += part[(size_t)(64 + b) * N_ROWS + row];
  }
  const int c = h[lab[row]];
  const float pos = sm + (float)(N_ROWS - c);
  const float neg = (st - sm) + (float)c;
  float term = logf(neg) - logf(pos);
  for (int m = 32; m; m >>= 1) term += __shfl_xor(term, m, 64);
  __shared__ float wsum[4];
  const int lane = threadIdx.x & 63;
  const int wave = threadIdx.x >> 6;
  if (lane == 0) wsum[wave] = term;
  __syncthreads();
  if (threadIdx.x == 0) bsum[blockIdx.x] = wsum[0] + wsum[1] + wsum[2] + wsum[3];
}

// Kernel 4: final 32-value reduction -> scalar loss.
__global__ void final_kernel(const float* __restrict__ bsum, float* __restrict__ out) {
  float v = (threadIdx.x < 32) ? bsum[threadIdx.x] : 0.f;
  for (int m = 32; m; m >>= 1) v += __shfl_xor(v, m, 64);
  if (threadIdx.x == 0) out[0] = v * (1.0f / (float)N_ROWS);
}

extern "C" void kernel_launch(void* const* d_in, const int* in_sizes, int n_in,
                              void* d_out, int out_size, void* d_ws, size_t ws_size,
                              hipStream_t stream) {
  const float* x = (const float*)d_in[0];
  const int* lab = (const int*)d_in[1];
  const float* t = (const float*)d_in[2];
  float* out = (float*)d_out;

  char* ws = (char*)d_ws;
  unsigned short* xb = (unsigned short*)ws;                      // 4 MiB bf16 X
  float* sv = (float*)(ws + (4u << 20));                         // 32 KiB scales
  float* part = (float*)(ws + (4u << 20) + (32u << 10));         // 4 MiB partials
  float* bsum = (float*)(ws + (8u << 20) + (32u << 10));         // 128 B

  prep_kernel<<<N_ROWS / 4, 256, 0, stream>>>(x, t, xb, sv);
  dim3 grid(64, 64);
  main_kernel<<<grid, 256, 0, stream>>>(xb, sv, lab, part);
  row_loss_kernel<<<N_ROWS / 256, 256, 0, stream>>>(part, lab, bsum);
  final_kernel<<<1, 64, 0, stream>>>(bsum, out);
}

// Round 3
// 118.727 us; speedup vs baseline: 1.5848x; 1.2247x over previous
//
#include <hip/hip_runtime.h>
#include <hip/hip_bf16.h>

#define N_ROWS 8192
#define DIM 256
#define NUM_CLASSES 64
#define NBLK 64                 // 8192/128 row/col blocks
#define NTRI (NBLK * (NBLK + 1) / 2)  // 2080 upper-triangle tiles

typedef __bf16 bf16x8 __attribute__((ext_vector_type(8)));
typedef float f32x4 __attribute__((ext_vector_type(4)));

__device__ __forceinline__ unsigned short f2bf(float f) {
  unsigned int u = __float_as_uint(f);
  u += 0x7fffu + ((u >> 16) & 1u);   // round-to-nearest-even
  return (unsigned short)(u >> 16);
}
__device__ __forceinline__ float bf2f(unsigned short h) {
  return __uint_as_float(((unsigned int)h) << 16);
}

__device__ __forceinline__ void gload_lds16(const unsigned short* g, unsigned short* l) {
  __builtin_amdgcn_global_load_lds(
      (const __attribute__((address_space(1))) unsigned int*)g,
      (__attribute__((address_space(3))) unsigned int*)l, 16, 0, 0);
}

// Kernel 1: quantize to bf16, per-row sum-of-squares of the *quantized* values
// (keeps diagonal cos exact), scale s_i = sqrt((log2e/t)/ss_i). Block 0 also
// zeroes the cross-kernel accumulator used by row_loss.
__global__ void __launch_bounds__(256) prep_kernel(
    const float* __restrict__ x, const float* __restrict__ tptr,
    unsigned short* __restrict__ xb, float* __restrict__ sv,
    float* __restrict__ gsum, unsigned int* __restrict__ gcnt) {
  if (blockIdx.x == 0 && threadIdx.x == 0) { *gsum = 0.f; *gcnt = 0u; }
  const int row = blockIdx.x * 4 + (threadIdx.x >> 6);
  const int lane = threadIdx.x & 63;
  const float4 v = *reinterpret_cast<const float4*>(x + (size_t)row * DIM + lane * 4);
  const unsigned short q0 = f2bf(v.x), q1 = f2bf(v.y), q2 = f2bf(v.z), q3 = f2bf(v.w);
  const float f0 = bf2f(q0), f1 = bf2f(q1), f2 = bf2f(q2), f3 = bf2f(q3);
  float ss = f0 * f0 + f1 * f1 + f2 * f2 + f3 * f3;
  ushort4 u4; u4.x = q0; u4.y = q1; u4.z = q2; u4.w = q3;
  *reinterpret_cast<ushort4*>(xb + (size_t)row * DIM + lane * 4) = u4;
  for (int m = 32; m; m >>= 1) ss += __shfl_xor(ss, m, 64);
  if (lane == 0) {
    const float C = 1.4426950408889634f / tptr[0];  // log2(e)/t
    sv[row] = sqrtf(C / ss);
  }
}

// Kernel 2: upper-triangle 128x128 Gram tiles (bf16 MFMA 16x16x32), 1D
// triangular grid, single-buffered staging (occupancy >= 3 blocks/CU; LDS
// 16384B exactly — epilogue scratch aliases the staging buffers). Fused exp
// epilogue produces BOTH row partials (rows of I over cols J) and col
// partials (rows of J over cols I) so each tile is computed once.
__global__ void __launch_bounds__(256, 3) main_kernel(
    const unsigned short* __restrict__ xb, const float* __restrict__ sv,
    const int* __restrict__ lab, float* __restrict__ part) {
  // triangular decode: block q -> (I, J), I <= J, row-major upper triangle
  const int q = blockIdx.x;
  int I = (int)((129.0f - sqrtf(16641.0f - 8.0f * (float)q)) * 0.5f);
  while (I * (129 - I) / 2 > q) --I;
  while ((I + 1) * (128 - I) / 2 <= q) ++I;
  const int J = I + (q - I * (129 - I) / 2);

  __shared__ alignas(16) unsigned short Alds[128 * 32];  // 8 KiB
  __shared__ alignas(16) unsigned short Blds[128 * 32];  // 8 KiB
  // epilogue scratch aliased onto staging buffers (dead after K loop):
  float* red = reinterpret_cast<float*>(Alds);           // 256 floats
  float (*colred)[128][2] = reinterpret_cast<float (*)[128][2]>(Blds);

  const int tid = threadIdx.x;
  const int wave = tid >> 6;
  const int lane = tid & 63;
  const int quad = lane >> 4;
  const int lc = lane & 15;
  const int wrow = (wave >> 1) * 64;
  const int wcol = (wave & 1) * 64;
  const int rowBase = I * 128;
  const int colBase = J * 128;

  f32x4 acc[4][4];
  const f32x4 zero4 = {0.f, 0.f, 0.f, 0.f};
  for (int mi = 0; mi < 4; ++mi)
    for (int ni = 0; ni < 4; ++ni) acc[mi][ni] = zero4;

  const int srow = lane >> 2;       // 16 rows per staging instruction
  const int sseg = (lane & 3) * 8;  // 4 x 16B segments per 32-elem row

  for (int kb = 0; kb < 8; ++kb) {
    const int k0 = kb * 32;
    const unsigned short* gA =
        xb + (size_t)(rowBase + wave * 32 + srow) * DIM + k0 + sseg;
    gload_lds16(gA, &Alds[(wave * 32) * 32]);
    gload_lds16(gA + 16 * DIM, &Alds[(wave * 32 + 16) * 32]);
    const unsigned short* gB =
        xb + (size_t)(colBase + wave * 32 + srow) * DIM + k0 + sseg;
    gload_lds16(gB, &Blds[(wave * 32) * 32]);
    gload_lds16(gB + 16 * DIM, &Blds[(wave * 32 + 16) * 32]);
    __syncthreads();  // staged data visible
    bf16x8 afr[4], bfr[4];
    for (int mi = 0; mi < 4; ++mi)
      afr[mi] = *reinterpret_cast<const bf16x8*>(
          &Alds[(wrow + mi * 16 + lc) * 32 + quad * 8]);
    for (int ni = 0; ni < 4; ++ni)
      bfr[ni] = *reinterpret_cast<const bf16x8*>(
          &Blds[(wcol + ni * 16 + lc) * 32 + quad * 8]);
    for (int mi = 0; mi < 4; ++mi)
      for (int ni = 0; ni < 4; ++ni)
        acc[mi][ni] = __builtin_amdgcn_mfma_f32_16x16x32_bf16(
            afr[mi], bfr[ni], acc[mi][ni], 0, 0, 0);
    __syncthreads();  // readers done before next stage overwrites
  }

  // --- epilogue (staging buffers now reusable as scratch) ---
  red[tid] = 0.f;
  __syncthreads();

  float scol[4];
  int labc[4];
  for (int ni = 0; ni < 4; ++ni) {
    const int c = colBase + wcol + ni * 16 + lc;
    scol[ni] = sv[c];
    labc[ni] = lab[c];
  }
  float ctot[4] = {0.f, 0.f, 0.f, 0.f};
  float csame[4] = {0.f, 0.f, 0.f, 0.f};

  for (int mi = 0; mi < 4; ++mi) {
    for (int r = 0; r < 4; ++r) {
      const int lr = wrow + mi * 16 + quad * 4 + r;  // C/D: row=(lane>>4)*4+reg
      const int grow = rowBase + lr;
      const float si = sv[grow];
      const int li = lab[grow];
      float st = 0.f, sm = 0.f;
      for (int ni = 0; ni < 4; ++ni) {
        const float e = exp2f(acc[mi][ni][r] * si * scol[ni]);
        const float em = (li == labc[ni]) ? e : 0.f;
        st += e;
        sm += em;
        ctot[ni] += e;
        csame[ni] += em;
      }
      for (int m = 8; m; m >>= 1) {
        st += __shfl_xor(st, m, 64);
        sm += __shfl_xor(sm, m, 64);
      }
      if (lc == 0) {
        atomicAdd(&red[lr], st);
        atomicAdd(&red[128 + lr], sm);
      }
    }
  }

  if (J > I) {
    for (int ni = 0; ni < 4; ++ni) {
      float t2 = ctot[ni] + __shfl_xor(ctot[ni], 16, 64);
      t2 += __shfl_xor(t2, 32, 64);
      float s2 = csame[ni] + __shfl_xor(csame[ni], 16, 64);
      s2 += __shfl_xor(s2, 32, 64);
      if (quad == 0) {
        colred[0][wcol + ni * 16 + lc][wave >> 1] = t2;
        colred[1][wcol + ni * 16 + lc][wave >> 1] = s2;
      }
    }
  }
  __syncthreads();
  if (tid < 128) {
    part[(size_t)J * N_ROWS + rowBase + tid] = red[tid];
    part[(size_t)(64 + J) * N_ROWS + rowBase + tid] = red[128 + tid];
    if (J > I) {
      part[(size_t)I * N_ROWS + colBase + tid] =
          colred[0][tid][0] + colred[0][tid][1];
      part[(size_t)(64 + I) * N_ROWS + colBase + tid] =
          colred[1][tid][0] + colred[1][tid][1];
    }
  }
}

// Kernel 3: per-row loss terms (label histogram in LDS), block sums
// accumulated device-scope; last block writes the final scalar.
__global__ void __launch_bounds__(256) row_loss_kernel(
    const float* __restrict__ part, const int* __restrict__ lab,
    float* __restrict__ gsum, unsigned int* __restrict__ gcnt,
    float* __restrict__ out) {
  __shared__ int h[NUM_CLASSES];
  if (threadIdx.x < NUM_CLASSES) h[threadIdx.x] = 0;
  __syncthreads();
  for (int i = threadIdx.x; i < N_ROWS; i += 256) atomicAdd(&h[lab[i]], 1);
  __syncthreads();

  const int row = blockIdx.x * 256 + threadIdx.x;
  float st = 0.f, sm = 0.f;
  for (int b = 0; b < 64; ++b) {
    st += part[(size_t)b * N_ROWS + row];
    sm += part[(size_t)(64 + b) * N_ROWS + row];
  }
  const int c = h[lab[row]];
  const float pos = sm + (float)(N_ROWS - c);
  const float neg = (st - sm) + (float)c;
  float term = logf(neg) - logf(pos);
  for (int m = 32; m; m >>= 1) term += __shfl_xor(term, m, 64);
  __shared__ float wsum[4];
  const int lane = threadIdx.x & 63;
  const int wave = threadIdx.x >> 6;
  if (lane == 0) wsum[wave] = term;
  __syncthreads();
  if (threadIdx.x == 0) {
    const float bs = wsum[0] + wsum[1] + wsum[2] + wsum[3];
    atomicAdd(gsum, bs);
    __threadfence();
    const unsigned int t = atomicAdd(gcnt, 1u);
    if (t == (unsigned int)(N_ROWS / 256 - 1)) {  // last block to arrive
      const float total = atomicAdd(gsum, 0.0f);  // coherent read
      out[0] = total * (1.0f / (float)N_ROWS);
    }
  }
}

extern "C" void kernel_launch(void* const* d_in, const int* in_sizes, int n_in,
                              void* d_out, int out_size, void* d_ws, size_t ws_size,
                              hipStream_t stream) {
  const float* x = (const float*)d_in[0];
  const int* lab = (const int*)d_in[1];
  const float* t = (const float*)d_in[2];
  float* out = (float*)d_out;

  char* ws = (char*)d_ws;
  unsigned short* xb = (unsigned short*)ws;                      // 4 MiB bf16 X
  float* sv = (float*)(ws + (4u << 20));                         // 32 KiB scales
  float* part = (float*)(ws + (4u << 20) + (32u << 10));         // 4 MiB partials
  float* gsum = (float*)(ws + (8u << 20) + (32u << 10));
  unsigned int* gcnt = (unsigned int*)(ws + (8u << 20) + (32u << 10) + 8);

  prep_kernel<<<N_ROWS / 4, 256, 0, stream>>>(x, t, xb, sv, gsum, gcnt);
  main_kernel<<<NTRI, 256, 0, stream>>>(xb, sv, lab, part);
  row_loss_kernel<<<N_ROWS / 256, 256, 0, stream>>>(part, lab, gsum, gcnt, out);
}